// Round 4
// baseline (349.204 us; speedup 1.0000x reference)
//
#include <hip/hip_runtime.h>

// FFF tree-routed feedforward: B=65536, nIn=nOut=1024, DEPTH=10, n_nodes=1023.
//
// Two-phase shared-path structure (round-4):
//  - route_kernel: per-wave routing (2 samples/wave for 2x memory-level
//    parallelism), w1 gathers only. Emits lam per level (transposed layout),
//    leaf id (depth-9 node), and a 512-bin leaf histogram.
//  - scan + scatter: counting sort of sample ids by leaf. Any intra-bucket
//    order gives identical per-sample output -> deterministic.
//  - accum_kernel: 2 blocks per leaf; path nodes derived by parent-walk from
//    the leaf id; the path's 10 w2 rows staged ONCE into LDS (40KB); each
//    sample is then 10 scalar lams + LDS reads + nt-store of y.
//    This moves the 2.6GB w2 gather off the ~64B/cyc L1 pipe (the round-3
//    bottleneck: ~34B/cyc effective) onto the LDS pipe + 20MB of L2 traffic.

#define FFF_DEPTH 10
#define N_IN 1024
#define N_OUT 1024
#define N_LEAF 512
#define LEAF_BASE 511

typedef float f32x4 __attribute__((ext_vector_type(4)));

// v += dpp_mov(v, CTRL); 0x111..0x118 = row_shr 1/2/4/8,
// 0x142 = row_bcast15, 0x143 = row_bcast31.
template<int CTRL, int ROW_MASK>
__device__ __forceinline__ float dpp_add(float v) {
    int sh = __builtin_amdgcn_update_dpp(0, __builtin_bit_cast(int, v),
                                         CTRL, ROW_MASK, 0xf, true);
    return v + __builtin_bit_cast(float, sh);
}

// Full 64-lane sum, result broadcast via readlane(63) (wave-uniform).
__device__ __forceinline__ float wave_sum(float p) {
    p = dpp_add<0x111, 0xf>(p);
    p = dpp_add<0x112, 0xf>(p);
    p = dpp_add<0x114, 0xf>(p);
    p = dpp_add<0x118, 0xf>(p);
    p = dpp_add<0x142, 0xa>(p);
    p = dpp_add<0x143, 0xc>(p);
    return __builtin_bit_cast(float,
        __builtin_amdgcn_readlane(__builtin_bit_cast(int, p), 63));
}

// ---------------- Phase 1: routing ----------------
__global__ __launch_bounds__(256, 4) void route_kernel(
    const float* __restrict__ x,
    const float* __restrict__ w1s,
    float* __restrict__ lamsT,      // [DEPTH][B]
    int* __restrict__ leafid,       // [B]
    int* __restrict__ hist,         // [512], pre-zeroed
    int B)
{
    const int lane = threadIdx.x & 63;
    const int wv = threadIdx.x >> 6;
    const int b0 = (blockIdx.x * 4 + wv) * 2;   // 2 samples per wave
    const int b1 = b0 + 1;
    if (b0 >= B) return;

    const f32x4* xa = reinterpret_cast<const f32x4*>(x + (size_t)b0 * N_IN);
    const f32x4* xb = reinterpret_cast<const f32x4*>(x + (size_t)b1 * N_IN);
    f32x4 xv0[4], xv1[4];
    #pragma unroll
    for (int c = 0; c < 4; ++c) {
        xv0[c] = __builtin_nontemporal_load(&xa[c * 64 + lane]);
        xv1[c] = __builtin_nontemporal_load(&xb[c * 64 + lane]);
    }

    int n0 = 0, n1 = 0;
    #pragma unroll
    for (int d = 0; d < FFF_DEPTH; ++d) {
        const f32x4* wa = reinterpret_cast<const f32x4*>(w1s + (size_t)n0 * N_IN);
        const f32x4* wb = reinterpret_cast<const f32x4*>(w1s + (size_t)n1 * N_IN);
        f32x4 w0[4], w1v[4];
        #pragma unroll
        for (int c = 0; c < 4; ++c) { w0[c] = wa[c * 64 + lane]; w1v[c] = wb[c * 64 + lane]; }

        float p0 = 0.f, p1 = 0.f, p2 = 0.f, p3 = 0.f;
        float q0 = 0.f, q1 = 0.f, q2 = 0.f, q3 = 0.f;
        #pragma unroll
        for (int c = 0; c < 4; ++c) {
            p0 += xv0[c][0] * w0[c][0];  q0 += xv1[c][0] * w1v[c][0];
            p1 += xv0[c][1] * w0[c][1];  q1 += xv1[c][1] * w1v[c][1];
            p2 += xv0[c][2] * w0[c][2];  q2 += xv1[c][2] * w1v[c][2];
            p3 += xv0[c][3] * w0[c][3];  q3 += xv1[c][3] * w1v[c][3];
        }
        float lam0 = wave_sum((p0 + p1) + (p2 + p3));
        float lam1 = wave_sum((q0 + q1) + (q2 + q3));

        if (lane == 0) {
            lamsT[(size_t)d * B + b0] = lam0;
            lamsT[(size_t)d * B + b1] = lam1;
        }
        n0 = n0 * 2 + 1 + (lam0 > 0.f ? 1 : 0);
        n1 = n1 * 2 + 1 + (lam1 > 0.f ? 1 : 0);
    }
    // leaf (depth-9 node actually used) = parent of the final index.
    if (lane == 0) {
        int l0 = (n0 - 1) >> 1, l1 = (n1 - 1) >> 1;
        leafid[b0] = l0; leafid[b1] = l1;
        atomicAdd(&hist[l0 - LEAF_BASE], 1);
        atomicAdd(&hist[l1 - LEAF_BASE], 1);
    }
}

// ---------------- Sort: scan + scatter ----------------
__global__ void scan_kernel(const int* __restrict__ hist,
                            int* __restrict__ offsets,   // [513]
                            int* __restrict__ cursor)    // [512]
{
    __shared__ int s[N_LEAF];
    const int t = threadIdx.x;
    const int v = hist[t];
    s[t] = v;
    __syncthreads();
    #pragma unroll
    for (int off = 1; off < N_LEAF; off <<= 1) {
        int u = (t >= off) ? s[t - off] : 0;
        __syncthreads();
        s[t] += u;
        __syncthreads();
    }
    const int excl = s[t] - v;
    offsets[t] = excl;
    cursor[t] = excl;
    if (t == N_LEAF - 1) offsets[N_LEAF] = s[t];
}

__global__ void scatter_kernel(const int* __restrict__ leafid,
                               int* __restrict__ cursor,
                               int* __restrict__ sorted, int B)
{
    const int b = blockIdx.x * blockDim.x + threadIdx.x;
    if (b < B) {
        const int pos = atomicAdd(&cursor[leafid[b] - LEAF_BASE], 1);
        sorted[pos] = b;
    }
}

// ---------------- Phase 2: y accumulation ----------------
__global__ __launch_bounds__(256, 4) void accum_kernel(
    const float* __restrict__ w2s,
    const float* __restrict__ lamsT,
    const int* __restrict__ sorted,
    const int* __restrict__ offsets,
    float* __restrict__ y, int B)
{
    __shared__ float lds[FFF_DEPTH * N_OUT];   // 40KB: the path's w2 rows
    const int leaf = blockIdx.x >> 1;          // 2 blocks per leaf
    const int half = blockIdx.x & 1;

    // Derive root->leaf path by parent-walk (no table needed).
    int nodes[FFF_DEPTH];
    int n = LEAF_BASE + leaf;
    #pragma unroll
    for (int d = FFF_DEPTH - 1; d >= 0; --d) { nodes[d] = n; n = (n - 1) >> 1; }

    const int tid = threadIdx.x;
    f32x4* lds4 = reinterpret_cast<f32x4*>(lds);
    #pragma unroll
    for (int d = 0; d < FFF_DEPTH; ++d) {
        const f32x4* src = reinterpret_cast<const f32x4*>(w2s + (size_t)nodes[d] * N_OUT);
        lds4[d * 256 + tid] = src[tid];        // 256 thr x float4 = one row
    }
    __syncthreads();

    const int start = offsets[leaf], end = offsets[leaf + 1];
    const int mid = start + ((end - start + 1) >> 1);
    const int rs = half ? mid : start;
    const int re = half ? end : mid;

    const int lane = tid & 63, wv = tid >> 6;
    for (int p = rs + wv; p < re; p += 4) {
        int b = __builtin_amdgcn_readfirstlane(sorted[p]);
        float lam[FFF_DEPTH];
        #pragma unroll
        for (int d = 0; d < FFF_DEPTH; ++d) lam[d] = lamsT[(size_t)d * B + b];

        f32x4 acc[4];
        #pragma unroll
        for (int c = 0; c < 4; ++c) acc[c] = (f32x4)0.f;
        #pragma unroll
        for (int d = 0; d < FFF_DEPTH; ++d) {     // same d-ascending order as ref
            const float l = lam[d];
            #pragma unroll
            for (int c = 0; c < 4; ++c) acc[c] += l * lds4[d * 256 + c * 64 + lane];
        }
        f32x4* y4 = reinterpret_cast<f32x4*>(y + (size_t)b * N_OUT);
        #pragma unroll
        for (int c = 0; c < 4; ++c) __builtin_nontemporal_store(acc[c], &y4[c * 64 + lane]);
    }
}

// ---------------- Fallback (round-3 proven kernel) ----------------
__global__ __launch_bounds__(256, 4) void fff_mono_kernel(
    const float* __restrict__ x, const float* __restrict__ w1s,
    const float* __restrict__ w2s, float* __restrict__ y, int B)
{
    const int lane = threadIdx.x & 63;
    const int b = blockIdx.x * 4 + (threadIdx.x >> 6);
    if (b >= B) return;
    const f32x4* x4 = reinterpret_cast<const f32x4*>(x + (size_t)b * N_IN);
    f32x4 xv[4], acc[4];
    #pragma unroll
    for (int c = 0; c < 4; ++c) { xv[c] = __builtin_nontemporal_load(&x4[c*64+lane]); acc[c] = (f32x4)0.f; }
    int node = 0;
    #pragma unroll
    for (int d = 0; d < FFF_DEPTH; ++d) {
        const f32x4* w1 = reinterpret_cast<const f32x4*>(w1s + (size_t)node * N_IN);
        const f32x4* w2 = reinterpret_cast<const f32x4*>(w2s + (size_t)node * N_OUT);
        f32x4 w[4], v[4];
        #pragma unroll
        for (int c = 0; c < 4; ++c) { w[c] = w1[c*64+lane]; v[c] = w2[c*64+lane]; }
        float p0=0,p1=0,p2=0,p3=0;
        #pragma unroll
        for (int c = 0; c < 4; ++c) {
            p0 += xv[c][0]*w[c][0]; p1 += xv[c][1]*w[c][1];
            p2 += xv[c][2]*w[c][2]; p3 += xv[c][3]*w[c][3];
        }
        float lam = wave_sum((p0+p1)+(p2+p3));
        #pragma unroll
        for (int c = 0; c < 4; ++c) acc[c] += lam * v[c];
        node = node * 2 + 1 + (lam > 0.f ? 1 : 0);
    }
    f32x4* y4 = reinterpret_cast<f32x4*>(y + (size_t)b * N_OUT);
    #pragma unroll
    for (int c = 0; c < 4; ++c) __builtin_nontemporal_store(acc[c], &y4[c*64+lane]);
}

extern "C" void kernel_launch(void* const* d_in, const int* in_sizes, int n_in,
                              void* d_out, int out_size, void* d_ws, size_t ws_size,
                              hipStream_t stream) {
    const float* x   = (const float*)d_in[0];
    const float* w1s = (const float*)d_in[1];
    const float* w2s = (const float*)d_in[2];
    float* y = (float*)d_out;
    const int B = in_sizes[0] / N_IN;   // 65536

    // Workspace carve-up.
    float* lamsT  = (float*)d_ws;                    // DEPTH*B floats
    int*   leafid = (int*)(lamsT + (size_t)FFF_DEPTH * B);
    int*   sorted = leafid + B;
    int*   offsets = sorted + B;                     // 513
    int*   cursor  = offsets + (N_LEAF + 1);         // 512
    int*   hist    = cursor + N_LEAF;                // 512
    const size_t need = ((size_t)FFF_DEPTH * B + 2 * (size_t)B + 3 * N_LEAF + 1) * 4;

    if (ws_size < need) {   // fallback: monolithic proven path
        fff_mono_kernel<<<(B + 3) / 4, 256, 0, stream>>>(x, w1s, w2s, y, B);
        return;
    }

    hipMemsetAsync(hist, 0, N_LEAF * sizeof(int), stream);
    route_kernel<<<B / 8, 256, 0, stream>>>(x, w1s, lamsT, leafid, hist, B);
    scan_kernel<<<1, N_LEAF, 0, stream>>>(hist, offsets, cursor);
    scatter_kernel<<<B / 256, 256, 0, stream>>>(leafid, cursor, sorted, B);
    accum_kernel<<<2 * N_LEAF, 256, 0, stream>>>(w2s, lamsT, sorted, offsets, y, B);
}

// Round 5
// 316.193 us; speedup vs baseline: 1.1044x; 1.1044x over previous
//
#include <hip/hip_runtime.h>

// FFF tree-routed feedforward: B=65536, nIn=nOut=1024, DEPTH=10, n_nodes=1023.
//
// Round-5 structure:
//  - route_kernel (unchanged core from R4, ~155us): 2 samples/wave, w1-only
//    gather + DPP reduce. NEW: lams stored one 64B line per sample
//    (lams16[b*16+d], full-line write by lanes 0..31), and sample ids appended
//    directly to fixed-capacity per-leaf bins (atomicAdd cursor) -- kills the
//    scan+scatter kernels. Bin order is non-deterministic but y[b] depends
//    only on b's own (lams, leaf), so output is deterministic.
//  - accum_kernel (R4's latency fixes): 2 blocks/leaf, 40KB LDS stage of the
//    leaf path's 10 w2 rows; per sample ONE coalesced 64B lam-line load +
//    readlane broadcast (was 10 scattered line-miss gathers = the 180us).
//    w2 traffic rides the LDS pipe instead of the ~34B/cyc L1 wall.

#define FFF_DEPTH 10
#define N_IN 1024
#define N_OUT 1024
#define N_LEAF 512
#define LEAF_BASE 511
#define BIN_CAP 512

typedef float f32x4 __attribute__((ext_vector_type(4)));

template<int CTRL, int ROW_MASK>
__device__ __forceinline__ float dpp_add(float v) {
    int sh = __builtin_amdgcn_update_dpp(0, __builtin_bit_cast(int, v),
                                         CTRL, ROW_MASK, 0xf, true);
    return v + __builtin_bit_cast(float, sh);
}

// Full 64-lane sum, result broadcast via readlane(63) (wave-uniform).
__device__ __forceinline__ float wave_sum(float p) {
    p = dpp_add<0x111, 0xf>(p);
    p = dpp_add<0x112, 0xf>(p);
    p = dpp_add<0x114, 0xf>(p);
    p = dpp_add<0x118, 0xf>(p);
    p = dpp_add<0x142, 0xa>(p);
    p = dpp_add<0x143, 0xc>(p);
    return __builtin_bit_cast(float,
        __builtin_amdgcn_readlane(__builtin_bit_cast(int, p), 63));
}

// ---------------- Phase 1: routing ----------------
__global__ __launch_bounds__(256, 4) void route_kernel(
    const float* __restrict__ x,
    const float* __restrict__ w1s,
    float* __restrict__ lams16,     // [B][16], one 64B line per sample
    int* __restrict__ bins,         // [512][BIN_CAP]
    int* __restrict__ cnt,          // [512], pre-zeroed
    int B)
{
    const int lane = threadIdx.x & 63;
    const int wv = threadIdx.x >> 6;
    const int b0 = (blockIdx.x * 4 + wv) * 2;   // 2 samples per wave
    const int b1 = b0 + 1;
    if (b0 >= B) return;

    const f32x4* xa = reinterpret_cast<const f32x4*>(x + (size_t)b0 * N_IN);
    const f32x4* xb = reinterpret_cast<const f32x4*>(x + (size_t)b1 * N_IN);
    f32x4 xv0[4], xv1[4];
    #pragma unroll
    for (int c = 0; c < 4; ++c) {
        xv0[c] = __builtin_nontemporal_load(&xa[c * 64 + lane]);
        xv1[c] = __builtin_nontemporal_load(&xb[c * 64 + lane]);
    }

    // Per-lane copies of the (wave-uniform) lams, selected by lane id so the
    // final store is one full 128B span written by lanes 0..31 (no RFO, no
    // scatter): lane<16 -> sample b0's line, lane 16..31 -> sample b1's.
    float myl = 0.f;
    const int sel = lane & 15;

    int n0 = 0, n1 = 0;
    #pragma unroll
    for (int d = 0; d < FFF_DEPTH; ++d) {
        const f32x4* wa = reinterpret_cast<const f32x4*>(w1s + (size_t)n0 * N_IN);
        const f32x4* wb = reinterpret_cast<const f32x4*>(w1s + (size_t)n1 * N_IN);
        f32x4 w0[4], w1v[4];
        #pragma unroll
        for (int c = 0; c < 4; ++c) { w0[c] = wa[c * 64 + lane]; w1v[c] = wb[c * 64 + lane]; }

        float p0 = 0.f, p1 = 0.f, p2 = 0.f, p3 = 0.f;
        float q0 = 0.f, q1 = 0.f, q2 = 0.f, q3 = 0.f;
        #pragma unroll
        for (int c = 0; c < 4; ++c) {
            p0 += xv0[c][0] * w0[c][0];  q0 += xv1[c][0] * w1v[c][0];
            p1 += xv0[c][1] * w0[c][1];  q1 += xv1[c][1] * w1v[c][1];
            p2 += xv0[c][2] * w0[c][2];  q2 += xv1[c][2] * w1v[c][2];
            p3 += xv0[c][3] * w0[c][3];  q3 += xv1[c][3] * w1v[c][3];
        }
        float lam0 = wave_sum((p0 + p1) + (p2 + p3));
        float lam1 = wave_sum((q0 + q1) + (q2 + q3));

        const float pick = (lane < 16) ? lam0 : lam1;
        myl = (sel == d) ? pick : myl;

        n0 = n0 * 2 + 1 + (lam0 > 0.f ? 1 : 0);
        n1 = n1 * 2 + 1 + (lam1 > 0.f ? 1 : 0);
    }

    // One coalesced 128B store covers both samples' lam lines.
    if (lane < 32) lams16[(size_t)b0 * 16 + lane] = (sel < FFF_DEPTH) ? myl : 0.f;

    // Direct bin append (leaf = depth-9 node = parent of final index).
    if (lane == 0) {
        int l0 = ((n0 - 1) >> 1) - LEAF_BASE;
        int p = atomicAdd(&cnt[l0], 1);
        if (p < BIN_CAP) bins[l0 * BIN_CAP + p] = b0;
    }
    if (lane == 1) {
        int l1 = ((n1 - 1) >> 1) - LEAF_BASE;
        int p = atomicAdd(&cnt[l1], 1);
        if (p < BIN_CAP) bins[l1 * BIN_CAP + p] = b1;
    }
}

// ---------------- Phase 2: y accumulation ----------------
__global__ __launch_bounds__(256, 4) void accum_kernel(
    const float* __restrict__ w2s,
    const float* __restrict__ lams16,
    const int* __restrict__ bins,
    const int* __restrict__ cnt,
    float* __restrict__ y)
{
    __shared__ float lds[FFF_DEPTH * N_OUT];   // 40KB: this leaf-path's w2 rows
    const int leaf = blockIdx.x >> 1;          // 2 blocks per leaf
    const int half = blockIdx.x & 1;

    // Derive root->leaf path by parent-walk.
    int nodes[FFF_DEPTH];
    int n = LEAF_BASE + leaf;
    #pragma unroll
    for (int d = FFF_DEPTH - 1; d >= 0; --d) { nodes[d] = n; n = (n - 1) >> 1; }

    const int tid = threadIdx.x;
    f32x4* lds4 = reinterpret_cast<f32x4*>(lds);
    #pragma unroll
    for (int d = 0; d < FFF_DEPTH; ++d) {
        const f32x4* src = reinterpret_cast<const f32x4*>(w2s + (size_t)nodes[d] * N_OUT);
        lds4[d * 256 + tid] = src[tid];        // 256 thr x float4 = one 4KB row
    }
    __syncthreads();

    const int nsamp = cnt[leaf];
    const int nh = (nsamp + 1) >> 1;
    const int rs = half ? nh : 0;
    const int re = half ? nsamp : nh;

    const int lane = tid & 63, wv = tid >> 6;
    for (int p = rs + wv; p < re; p += 4) {
        const int b = __builtin_amdgcn_readfirstlane(bins[leaf * BIN_CAP + p]);
        // One coalesced 64B line: lanes repeat over the sample's 16-float row.
        const float lv = lams16[(size_t)b * 16 + (lane & 15)];

        f32x4 acc[4];
        #pragma unroll
        for (int c = 0; c < 4; ++c) acc[c] = (f32x4)0.f;
        #pragma unroll
        for (int d = 0; d < FFF_DEPTH; ++d) {     // same d-ascending order as ref
            const float l = __builtin_bit_cast(float,
                __builtin_amdgcn_readlane(__builtin_bit_cast(int, lv), d));
            #pragma unroll
            for (int c = 0; c < 4; ++c) acc[c] += l * lds4[d * 256 + c * 64 + lane];
        }
        f32x4* y4 = reinterpret_cast<f32x4*>(y + (size_t)b * N_OUT);
        #pragma unroll
        for (int c = 0; c < 4; ++c) __builtin_nontemporal_store(acc[c], &y4[c * 64 + lane]);
    }
}

// ---------------- Fallback (round-3 proven kernel) ----------------
__global__ __launch_bounds__(256, 4) void fff_mono_kernel(
    const float* __restrict__ x, const float* __restrict__ w1s,
    const float* __restrict__ w2s, float* __restrict__ y, int B)
{
    const int lane = threadIdx.x & 63;
    const int b = blockIdx.x * 4 + (threadIdx.x >> 6);
    if (b >= B) return;
    const f32x4* x4 = reinterpret_cast<const f32x4*>(x + (size_t)b * N_IN);
    f32x4 xv[4], acc[4];
    #pragma unroll
    for (int c = 0; c < 4; ++c) { xv[c] = __builtin_nontemporal_load(&x4[c*64+lane]); acc[c] = (f32x4)0.f; }
    int node = 0;
    #pragma unroll
    for (int d = 0; d < FFF_DEPTH; ++d) {
        const f32x4* w1 = reinterpret_cast<const f32x4*>(w1s + (size_t)node * N_IN);
        const f32x4* w2 = reinterpret_cast<const f32x4*>(w2s + (size_t)node * N_OUT);
        f32x4 w[4], v[4];
        #pragma unroll
        for (int c = 0; c < 4; ++c) { w[c] = w1[c*64+lane]; v[c] = w2[c*64+lane]; }
        float p0=0,p1=0,p2=0,p3=0;
        #pragma unroll
        for (int c = 0; c < 4; ++c) {
            p0 += xv[c][0]*w[c][0]; p1 += xv[c][1]*w[c][1];
            p2 += xv[c][2]*w[c][2]; p3 += xv[c][3]*w[c][3];
        }
        float lam = wave_sum((p0+p1)+(p2+p3));
        #pragma unroll
        for (int c = 0; c < 4; ++c) acc[c] += lam * v[c];
        node = node * 2 + 1 + (lam > 0.f ? 1 : 0);
    }
    f32x4* y4 = reinterpret_cast<f32x4*>(y + (size_t)b * N_OUT);
    #pragma unroll
    for (int c = 0; c < 4; ++c) __builtin_nontemporal_store(acc[c], &y4[c*64+lane]);
}

extern "C" void kernel_launch(void* const* d_in, const int* in_sizes, int n_in,
                              void* d_out, int out_size, void* d_ws, size_t ws_size,
                              hipStream_t stream) {
    const float* x   = (const float*)d_in[0];
    const float* w1s = (const float*)d_in[1];
    const float* w2s = (const float*)d_in[2];
    float* y = (float*)d_out;
    const int B = in_sizes[0] / N_IN;   // 65536

    // Workspace carve-up: lams16 [B][16] f32, bins [512][BIN_CAP] i32, cnt [512].
    float* lams16 = (float*)d_ws;
    int*   bins   = (int*)(lams16 + (size_t)B * 16);
    int*   cnt    = bins + (size_t)N_LEAF * BIN_CAP;
    const size_t need = ((size_t)B * 16 + (size_t)N_LEAF * BIN_CAP + N_LEAF) * 4;

    if (ws_size < need) {   // fallback: monolithic proven path
        fff_mono_kernel<<<(B + 3) / 4, 256, 0, stream>>>(x, w1s, w2s, y, B);
        return;
    }

    hipMemsetAsync(cnt, 0, N_LEAF * sizeof(int), stream);
    route_kernel<<<B / 8, 256, 0, stream>>>(x, w1s, lams16, bins, cnt, B);
    accum_kernel<<<2 * N_LEAF, 256, 0, stream>>>(w2s, lams16, bins, cnt, y);
}